// Round 1
// baseline (60.217 us; speedup 1.0000x reference)
//
#include <hip/hip_runtime.h>

// out[o,h,w] = sum_i  (w>0) * x[i, (h-1)%14, (w-2)%14] * wt[o,0,i]
//            +        x[i, (h-1)%14, (w-1)%14] * wt[o,1,i]
//            + (w<13)* x[i, (h-1)%14,  w     ] * wt[o,2,i]
//
// x  : [128, 14, 14] f32, wt : [32, 3, 128] f32, out: [32, 14, 14] f32
//
// Round 4: single-phase latency fix. 16 lanes per output element, each lane
// reduces 8 channels x 3 taps (24 FMAs, three independent 8-deep chains),
// then a 4-step __shfl_xor in-register tree replaces the previous
// LDS + __syncthreads + 14-thread serial-add tail. No LDS, no barrier,
// all 256 threads active. 392 blocks x 256 threads = 6272 outputs exactly;
// 1568 waves fully resident on 256 CUs.

__global__ __launch_bounds__(256) void conv_roll_kernel(
    const float* __restrict__ x,
    const float* __restrict__ wt,
    float* __restrict__ out)
{
    const int t = threadIdx.x;
    const int g = t >> 4;                    // output slot within block, 0..15
    const int r = t & 15;                    // reduction lane: channels r*8..r*8+7

    const int oid = (blockIdx.x << 4) + g;   // 0..6271
    const int o   = oid / 196;               // 0..31
    const int rem = oid - o * 196;
    const int h   = rem / 14;                // 0..13
    const int w   = rem - h * 14;            // 0..13

    const int rb = ((h + 13) % 14) * 14;     // undo output H-roll
    const int c0 = rb + ((w + 12) % 14);     // k=0 tap column
    const int c1 = rb + ((w + 13) % 14);     // k=1 tap (always valid)
    const int c2 = rb + w;                   // k=2 tap column

    // Weights: wt[o, k, r*8 + j] -> three contiguous 8-float runs, 32B aligned.
    const float* __restrict__ wo = wt + o * 384 + r * 8;
    float wv[3][8];
    *reinterpret_cast<float4*>(&wv[0][0]) = *reinterpret_cast<const float4*>(wo);
    *reinterpret_cast<float4*>(&wv[0][4]) = *reinterpret_cast<const float4*>(wo + 4);
    *reinterpret_cast<float4*>(&wv[1][0]) = *reinterpret_cast<const float4*>(wo + 128);
    *reinterpret_cast<float4*>(&wv[1][4]) = *reinterpret_cast<const float4*>(wo + 132);
    *reinterpret_cast<float4*>(&wv[2][0]) = *reinterpret_cast<const float4*>(wo + 256);
    *reinterpret_cast<float4*>(&wv[2][4]) = *reinterpret_cast<const float4*>(wo + 260);

    const float* __restrict__ xb = x + (r * 8) * 196;

    float a0 = 0.f, a1 = 0.f, a2 = 0.f;
#pragma unroll
    for (int j = 0; j < 8; ++j) {
        const float* __restrict__ xp = xb + j * 196;
        a0 = __builtin_fmaf(xp[c0], wv[0][j], a0);
        a1 = __builtin_fmaf(xp[c1], wv[1][j], a1);
        a2 = __builtin_fmaf(xp[c2], wv[2][j], a2);
    }

    float s = a1 + ((w > 0)  ? a0 : 0.f)     // left zero-pad mask
                 + ((w < 13) ? a2 : 0.f);    // right zero-pad mask

    // In-register reduction across the 16 lanes of this output
    // (xor masks 1,2,4,8 never cross the 16-lane group).
    s += __shfl_xor(s, 1);
    s += __shfl_xor(s, 2);
    s += __shfl_xor(s, 4);
    s += __shfl_xor(s, 8);

    if (r == 0) out[oid] = s;
}

extern "C" void kernel_launch(void* const* d_in, const int* in_sizes, int n_in,
                              void* d_out, int out_size, void* d_ws, size_t ws_size,
                              hipStream_t stream) {
    const float* x  = (const float*)d_in[0];   // 128*14*14 = 25088
    const float* wt = (const float*)d_in[1];   // 32*3*128  = 12288
    float* out = (float*)d_out;                // 32*14*14  = 6272

    conv_roll_kernel<<<392, 256, 0, stream>>>(x, wt, out);
}

// Round 2
// 56.084 us; speedup vs baseline: 1.0737x; 1.0737x over previous
//
#include <hip/hip_runtime.h>

// out[o,h,w] = sum_i  (w>0) * x[i, (h-1)%14, (w-2)%14] * wt[o,0,i]
//            +        x[i, (h-1)%14, (w-1)%14] * wt[o,1,i]
//            + (w<13)* x[i, (h-1)%14,  w     ] * wt[o,2,i]
//
// x  : [128, 14, 14] f32, wt : [32, 3, 128] f32, out: [32, 14, 14] f32
//
// Round 5: recover round-3's coalescing AND shrink the reduction tail.
// Mapping t = ci*16 + w keeps w fast-varying across lanes (contiguous 56B
// column runs per tap load) while placing the 4 ci-groups of each wave at
// lane offsets 0/16/32/48 -> reducible with 2 __shfl_down steps in-register.
// Tail is then one barrier + 4 LDS reads (round 3: 16 serial reads), and
// weights load as 6 float4 (round 3: 24 scalar loads).
// 448 blocks x 256 threads = 1792 waves, full CU coverage.

__global__ __launch_bounds__(256) void conv_roll_kernel(
    const float* __restrict__ x,
    const float* __restrict__ wt,
    float* __restrict__ out)
{
    __shared__ float red[64];         // [wave 0..3][lane&15]

    const int bx = blockIdx.x;        // 0..447
    const int o  = bx / 14;           // 0..31 (uniform)
    const int h  = bx - o * 14;       // 0..13 (uniform)
    const int rb = ((h + 13) % 14) * 14;   // undo output H-roll

    const int t  = threadIdx.x;       // 0..255
    const int ci = t >> 4;            // channel group 0..15 (8 ch each)
    const int w  = t & 15;            // output column, active w<14

    const int wc = (w < 14) ? w : 0;  // safe column for pad lanes
    const int c0 = rb + ((wc + 12) % 14);   // k=0 tap column
    const int c1 = rb + ((wc + 13) % 14);   // k=1 tap (always valid)
    const int c2 = rb + wc;                 // k=2 tap column

    // Weights wt[o, k, ci*8 + j]: three contiguous 8-float runs, 16B aligned.
    const float* __restrict__ wo = wt + o * 384 + ci * 8;
    float wv[3][8];
    *reinterpret_cast<float4*>(&wv[0][0]) = *reinterpret_cast<const float4*>(wo);
    *reinterpret_cast<float4*>(&wv[0][4]) = *reinterpret_cast<const float4*>(wo + 4);
    *reinterpret_cast<float4*>(&wv[1][0]) = *reinterpret_cast<const float4*>(wo + 128);
    *reinterpret_cast<float4*>(&wv[1][4]) = *reinterpret_cast<const float4*>(wo + 132);
    *reinterpret_cast<float4*>(&wv[2][0]) = *reinterpret_cast<const float4*>(wo + 256);
    *reinterpret_cast<float4*>(&wv[2][4]) = *reinterpret_cast<const float4*>(wo + 260);

    const float* __restrict__ xb = x + (ci * 8) * 196;

    float a0 = 0.f, a1 = 0.f, a2 = 0.f;
#pragma unroll
    for (int j = 0; j < 8; ++j) {
        const float* __restrict__ xp = xb + j * 196;
        a0 = __builtin_fmaf(xp[c0], wv[0][j], a0);
        a1 = __builtin_fmaf(xp[c1], wv[1][j], a1);
        a2 = __builtin_fmaf(xp[c2], wv[2][j], a2);
    }

    float s = a1 + ((w > 0)  ? a0 : 0.f)     // left zero-pad mask
                 + ((w < 13) ? a2 : 0.f);    // right zero-pad mask
    if (w >= 14) s = 0.f;                    // pad lanes contribute nothing

    // In-wave reduce across the 4 ci-groups (lane offsets 0/16/32/48).
    s += __shfl_down(s, 32);
    s += __shfl_down(s, 16);

    // Lanes 0..15 of each wave now hold the 32-channel partial for column w.
    const int lane = t & 63;
    const int wave = t >> 6;
    if (lane < 16) red[wave * 16 + lane] = s;

    __syncthreads();

    if (t < 14) {
        const float r = red[t] + red[16 + t] + red[32 + t] + red[48 + t];
        out[o * 196 + h * 14 + t] = r;
    }
}

extern "C" void kernel_launch(void* const* d_in, const int* in_sizes, int n_in,
                              void* d_out, int out_size, void* d_ws, size_t ws_size,
                              hipStream_t stream) {
    const float* x  = (const float*)d_in[0];   // 128*14*14 = 25088
    const float* wt = (const float*)d_in[1];   // 32*3*128  = 12288
    float* out = (float*)d_out;                // 32*14*14  = 6272

    conv_roll_kernel<<<448, 256, 0, stream>>>(x, wt, out);
}